// Round 3
// baseline (267.405 us; speedup 1.0000x reference)
//
#include <hip/hip_runtime.h>
#include <stdint.h>

typedef __bf16 bf16;
typedef __bf16 bf16x8 __attribute__((ext_vector_type(8)));
typedef float f32x4 __attribute__((ext_vector_type(4)));

#define MFMA16(a, b, c) __builtin_amdgcn_mfma_f32_16x16x32_bf16((a), (b), (c), 0, 0, 0)

// async global->LDS DMA, 16B per lane. LDS dest must be wave-uniform; HW writes base + lane*16.
__device__ __forceinline__ void ldsdma16(const void* g, void* l) {
  __builtin_amdgcn_global_load_lds((const __attribute__((address_space(1))) void*)g,
                                   (__attribute__((address_space(3))) void*)l, 16, 0, 0);
}

// ---------------------------------------------------------------------------
// Grid barrier: all 256 blocks are co-resident (1 block/CU forced by 128 KiB
// LDS; cooperative launch). Monotonic counter, zeroed by hipMemsetAsync before
// launch. Release on arrival (writes back XCD L2), acquire after spin
// (invalidates L1/L2) -> cross-XCD visibility of prior phase's plain stores.
// ---------------------------------------------------------------------------
__device__ __forceinline__ void gridbar(unsigned* cnt, unsigned target) {
  __syncthreads();  // all waves drain vmcnt(0) -> block's stores are in L2
  if (threadIdx.x == 0) {
    __hip_atomic_fetch_add(cnt, 1u, __ATOMIC_ACQ_REL, __HIP_MEMORY_SCOPE_AGENT);
    while (__hip_atomic_load(cnt, __ATOMIC_RELAXED, __HIP_MEMORY_SCOPE_AGENT) < target)
      __builtin_amdgcn_s_sleep(8);
    (void)__hip_atomic_load(cnt, __ATOMIC_ACQUIRE, __HIP_MEMORY_SCOPE_AGENT);
  }
  __syncthreads();
}

// ===========================================================================
// QKV 8-phase helpers (256x256 tile, BK=64, 8 waves 2Mx4N) — verified in R1/R2.
// ===========================================================================
__device__ __forceinline__ void stage_half(const bf16* __restrict__ src, int rowbase,
                                           int koff, char* lds, int bufq, int wave,
                                           int lane) {
#pragma unroll
  for (int i = 0; i < 2; ++i) {
    int chunk = i * 512 + wave * 64 + lane;  // 16B chunks, 8 per 64-col row
    int row = chunk >> 3;
    int cg = (chunk & 7) ^ (row & 7);        // pre-swizzled source column group
    ldsdma16(src + (size_t)(rowbase + row) * 1024 + koff + cg * 8,
             lds + bufq * 16384 + (i * 512 + wave * 64) * 16);
  }
}

__device__ __forceinline__ void ld_frag4(const bf16* lds, int bufq, int rbase, int quad,
                                         int l16, bf16x8 (&d)[4][2]) {
  const bf16x8* hb = (const bf16x8*)lds + bufq * 1024;
#pragma unroll
  for (int mf = 0; mf < 4; ++mf) {
    int row = rbase + mf * 16 + l16;
#pragma unroll
    for (int kk = 0; kk < 2; ++kk)
      d[mf][kk] = hb[row * 8 + ((kk * 4 + quad) ^ (row & 7))];
  }
}

__device__ __forceinline__ void ld_frag2(const bf16* lds, int bufq, int rbase, int quad,
                                         int l16, bf16x8 (&d)[2][2]) {
  const bf16x8* hb = (const bf16x8*)lds + bufq * 1024;
#pragma unroll
  for (int nf = 0; nf < 2; ++nf) {
    int row = rbase + nf * 16 + l16;
#pragma unroll
    for (int kk = 0; kk < 2; ++kk)
      d[nf][kk] = hb[row * 8 + ((kk * 4 + quad) ^ (row & 7))];
  }
}

template <int MQ, int NQ>
__device__ __forceinline__ void mma_quad(f32x4 (&acc)[8][4], const bf16x8 (&a)[4][2],
                                         const bf16x8 (&b)[2][2]) {
  __builtin_amdgcn_s_setprio(1);
#pragma unroll
  for (int mf = 0; mf < 4; ++mf)
#pragma unroll
    for (int nf = 0; nf < 2; ++nf)
#pragma unroll
      for (int kk = 0; kk < 2; ++kk)
        acc[MQ * 4 + mf][NQ * 2 + nf] =
            MFMA16(a[mf][kk], b[nf][kk], acc[MQ * 4 + mf][NQ * 2 + nf]);
  __builtin_amdgcn_s_setprio(0);
}

#define QBAR1() { __builtin_amdgcn_s_barrier(); \
                  asm volatile("s_waitcnt lgkmcnt(0)" ::: "memory"); }
#define QBAR2() { __builtin_amdgcn_s_barrier(); }

template <bool PRE>
__device__ __forceinline__ void qkv_iter(int k0, const bf16* __restrict__ xb,
                                         const bf16* __restrict__ BT, int m0, int n0,
                                         bf16* As, bf16* Bs, f32x4 (&acc)[8][4], int wave,
                                         int lane, int wm, int wn, int quad, int l16) {
  bf16x8 aF[4][2], b0F[2][2], b1F[2][2];
  // P1: quad (mq0,nq0) of tile a; stage A1(b)
  ld_frag4(As, 0, wm * 64, quad, l16, aF);
  ld_frag2(Bs, 0, wn * 32, quad, l16, b0F);
  stage_half(xb, m0 + 128, k0 + 64, (char*)As, 3, wave, lane);
  QBAR1(); mma_quad<0, 0>(acc, aF, b0F); QBAR2();
  // P2: (mq0,nq1), reuse aF; stage B0(b)
  ld_frag2(Bs, 1, wn * 32, quad, l16, b1F);
  stage_half(BT, n0, k0 + 64, (char*)Bs, 2, wave, lane);
  QBAR1(); mma_quad<0, 1>(acc, aF, b1F); QBAR2();
  // P3: (mq1,nq1); stage A0(a+2)
  ld_frag4(As, 1, wm * 64, quad, l16, aF);
  if (PRE) stage_half(xb, m0, k0 + 128, (char*)As, 0, wave, lane);
  QBAR1(); mma_quad<1, 1>(acc, aF, b1F); QBAR2();
  // P4: (mq1,nq0), reuse aF,b0F; stage B1(a+2); vmcnt gate for tile b
  if (PRE) stage_half(BT, n0 + 128, k0 + 128, (char*)Bs, 1, wave, lane);
  QBAR1(); mma_quad<1, 0>(acc, aF, b0F);
  if (PRE) { asm volatile("s_waitcnt vmcnt(4)" ::: "memory"); }
  else     { asm volatile("s_waitcnt vmcnt(0)" ::: "memory"); }
  QBAR2();
  // P5: tile b (mq0,nq0); stage A1(a+2)
  ld_frag4(As, 2, wm * 64, quad, l16, aF);
  ld_frag2(Bs, 2, wn * 32, quad, l16, b0F);
  if (PRE) stage_half(xb, m0 + 128, k0 + 128, (char*)As, 1, wave, lane);
  QBAR1(); mma_quad<0, 0>(acc, aF, b0F); QBAR2();
  // P6: (mq0,nq1); stage B0(a+2)
  ld_frag2(Bs, 3, wn * 32, quad, l16, b1F);
  if (PRE) stage_half(BT, n0, k0 + 128, (char*)Bs, 0, wave, lane);
  QBAR1(); mma_quad<0, 1>(acc, aF, b1F); QBAR2();
  // P7: (mq1,nq1); stage A0(b+2)
  ld_frag4(As, 3, wm * 64, quad, l16, aF);
  if (PRE) stage_half(xb, m0, k0 + 192, (char*)As, 2, wave, lane);
  QBAR1(); mma_quad<1, 1>(acc, aF, b1F); QBAR2();
  // P8: (mq1,nq0); stage B1(b+2); vmcnt gate for tile a+2
  if (PRE) stage_half(BT, n0 + 128, k0 + 192, (char*)Bs, 3, wave, lane);
  QBAR1(); mma_quad<1, 0>(acc, aF, b0F);
  if (PRE) { asm volatile("s_waitcnt vmcnt(4)" ::: "memory"); }
  QBAR2();
}

// ===========================================================================
// Attention phase (8-wave / 128-query-tile version of the verified R1 code).
// NT=8 (128 keys). MODE: 0 none, 1 lower(window), 2 causal.
// ===========================================================================
template <int MODE>
__device__ __forceinline__ void attn_phase8(int start, const bf16* __restrict__ Kb,
                                            const bf16* __restrict__ Vb, bf16* Ks, bf16* Vt,
                                            bf16* Psw, const bf16x8 qa0, const bf16x8 qa1,
                                            int i0, float (&mrow)[4], float (&lrow)[4],
                                            f32x4 (&oacc)[4]) {
  const int tid = threadIdx.x, lane = tid & 63, wave = tid >> 6;
  const int quad = lane >> 4, l16 = lane & 15;
  const f32x4 zero = {0.f, 0.f, 0.f, 0.f};

  __syncthreads();  // previous phase's Ks/Vt reads done
  // stage K: 128 rows x 64, 1024 chunks over 8 waves; swizzle c ^ (row&7)
#pragma unroll
  for (int c = 0; c < 2; ++c) {
    int chunk = c * 512 + wave * 64 + lane;
    int row = chunk >> 3;
    int cg = (chunk & 7) ^ (row & 7);
    ldsdma16(Kb + (size_t)(start + row) * 64 + cg * 8,
             (char*)Ks + (size_t)(c * 512 + wave * 64) * 16);
  }
  // stage V transposed: Vt[hd][key], 128 keys, stride 136
  {
    const int key = tid >> 2, hc = (tid & 3) * 16;
    const bf16* vp = Vb + (size_t)(start + key) * 64 + hc;
    bf16x8 v0 = ((const bf16x8*)vp)[0], v1 = ((const bf16x8*)vp)[1];
#pragma unroll
    for (int i = 0; i < 8; ++i) Vt[(hc + i) * 136 + key] = v0[i];
#pragma unroll
    for (int i = 0; i < 8; ++i) Vt[(hc + 8 + i) * 136 + key] = v1[i];
  }
  __syncthreads();

  // scores S = Q K^T (scale folded into Q)
  f32x4 sc[8];
  __builtin_amdgcn_s_setprio(1);
#pragma unroll
  for (int nt = 0; nt < 8; ++nt) {
    int key = nt * 16 + l16;
    bf16x8 kb0 = ((const bf16x8*)Ks)[key * 8 + ((0 * 4 + quad) ^ (key & 7))];
    bf16x8 kb1 = ((const bf16x8*)Ks)[key * 8 + ((1 * 4 + quad) ^ (key & 7))];
    f32x4 s = zero;
    s = MFMA16(qa0, kb0, s);
    s = MFMA16(qa1, kb1, s);
    sc[nt] = s;
  }
  __builtin_amdgcn_s_setprio(0);

  float alpha[4];
#pragma unroll
  for (int r = 0; r < 4; ++r) {
    const int i = i0 + r;
    float mx = -1e30f;
#pragma unroll
    for (int nt = 0; nt < 8; ++nt) {
      float s = sc[nt][r];
      if (MODE == 1) {
        const bool valid = (start + nt * 16 + l16 + 255 >= i);
        s = valid ? s : -1e30f;
        sc[nt][r] = s;
      } else if (MODE == 2) {
        const bool valid = (start + nt * 16 + l16 <= i);
        s = valid ? s : -1e30f;
        sc[nt][r] = s;
      }
      mx = fmaxf(mx, s);
    }
#pragma unroll
    for (int m = 8; m >= 1; m >>= 1) mx = fmaxf(mx, __shfl_xor(mx, m, 64));
    const float mnew = fmaxf(mrow[r], mx);
    alpha[r] = __expf(mrow[r] - mnew);
    mrow[r] = mnew;
    float rs = 0.f;
#pragma unroll
    for (int nt = 0; nt < 8; ++nt) {
      const float p = __expf(sc[nt][r] - mnew);
      sc[nt][r] = p;
      rs += p;
    }
#pragma unroll
    for (int m = 8; m >= 1; m >>= 1) rs += __shfl_xor(rs, m, 64);
    lrow[r] = lrow[r] * alpha[r] + rs;
  }

  // P: C-layout -> A-layout via per-wave LDS round-trip (bf16)
#pragma unroll
  for (int nt = 0; nt < 8; ++nt)
#pragma unroll
    for (int r = 0; r < 4; ++r)
      Psw[(quad * 4 + r) * 136 + nt * 16 + l16] = (bf16)sc[nt][r];
  asm volatile("s_waitcnt lgkmcnt(0)" ::: "memory");  // same-wave LDS RAW
  bf16x8 pa[4];
#pragma unroll
  for (int ks = 0; ks < 4; ++ks)
    pa[ks] = ((const bf16x8*)Psw)[l16 * 17 + ks * 4 + quad];

  // O = O*alpha + P V
  __builtin_amdgcn_s_setprio(1);
#pragma unroll
  for (int ht = 0; ht < 4; ++ht) {
    f32x4 o = oacc[ht];
#pragma unroll
    for (int r = 0; r < 4; ++r) o[r] *= alpha[r];
#pragma unroll
    for (int ks = 0; ks < 4; ++ks) {
      bf16x8 vb = ((const bf16x8*)Vt)[(ht * 16 + l16) * 17 + ks * 4 + quad];
      o = MFMA16(pa[ks], vb, o);
    }
    oacc[ht] = o;
  }
  __builtin_amdgcn_s_setprio(0);
}

__device__ __forceinline__ void attn_job(int job, const bf16* __restrict__ Q,
                                         const bf16* __restrict__ K,
                                         const bf16* __restrict__ V, bf16* __restrict__ Ao,
                                         bf16* Ks, bf16* Vt, bf16* Ps) {
  const int tid = threadIdx.x, lane = tid & 63, wave = tid >> 6;
  const int quad = lane >> 4, l16 = lane & 15;
  const int qt = job & 15, h = (job >> 4) & 15, b = job >> 8;
  const int q0 = qt * 128;
  const size_t base = ((size_t)(b * 16 + h)) * 2048 * 64;
  const bf16* Qb = Q + base + (size_t)q0 * 64;
  const bf16* Kb = K + base;
  const bf16* Vb = V + base;

  // Q fragments straight from global (L2-resident, one-shot)
  const bf16* qrow = Qb + (size_t)(wave * 16 + l16) * 64 + quad * 8;
  const bf16x8 qa0 = *(const bf16x8*)qrow;
  const bf16x8 qa1 = *(const bf16x8*)(qrow + 32);

  float mrow[4], lrow[4];
  f32x4 oacc[4];
  const f32x4 zero = {0.f, 0.f, 0.f, 0.f};
#pragma unroll
  for (int r = 0; r < 4; ++r) { mrow[r] = -1e30f; lrow[r] = 0.f; }
#pragma unroll
  for (int t = 0; t < 4; ++t) oacc[t] = zero;

  const int i0 = q0 + wave * 16 + quad * 4;
  bf16* Psw = Ps + wave * (16 * 136);

  if (q0 >= 256)
    attn_phase8<1>(q0 - 256, Kb, Vb, Ks, Vt, Psw, qa0, qa1, i0, mrow, lrow, oacc);
  if (q0 >= 128)
    attn_phase8<0>(q0 - 128, Kb, Vb, Ks, Vt, Psw, qa0, qa1, i0, mrow, lrow, oacc);
  attn_phase8<2>(q0, Kb, Vb, Ks, Vt, Psw, qa0, qa1, i0, mrow, lrow, oacc);

#pragma unroll
  for (int r = 0; r < 4; ++r) {
    const float inv = 1.f / lrow[r];
    const int row = q0 + wave * 16 + quad * 4 + r;
    const size_t outb = ((size_t)(b * 2048 + row)) * 1024 + h * 64;
#pragma unroll
    for (int ht = 0; ht < 4; ++ht)
      Ao[outb + ht * 16 + l16] = (bf16)(oacc[ht][r] * inv);
  }
}

// ===========================================================================
// MEGA: prep -> qkv -> attn -> out, one cooperative launch, grid barriers.
// 256 blocks x 512 threads, 128 KiB dynamic LDS (1 block/CU).
// ===========================================================================
__global__ void __launch_bounds__(512, 2)
mega(const float* __restrict__ x, const float* __restrict__ Wq,
     const float* __restrict__ Wk, const float* __restrict__ Wv,
     const float* __restrict__ Wo, const float* __restrict__ bq,
     const float* __restrict__ bk, const float* __restrict__ bv,
     const float* __restrict__ bo, bf16* __restrict__ xb, bf16* __restrict__ WT,
     bf16* __restrict__ Qd, bf16* __restrict__ Kd, bf16* __restrict__ Vd,
     bf16* __restrict__ Ao, float* __restrict__ out, unsigned* cnt) {
  extern __shared__ char smem[];
  const int tid = threadIdx.x, lane = tid & 63, wave = tid >> 6;
  const int quad = lane >> 4, l16 = lane & 15;
  const int bid = blockIdx.x;

  // ---- phase 0: prep (cast x; transpose-cast W) ----
  {
    const int gt = bid * 512 + tid;
#pragma unroll
    for (int it = 0; it < 8; ++it) {
      const int i4 = it * 131072 + gt;  // float4 index, 1M total
      const float4 v = ((const float4*)x)[i4];
      union { bf16 h[4]; uint2 u; } p;
      p.h[0] = (bf16)v.x; p.h[1] = (bf16)v.y; p.h[2] = (bf16)v.z; p.h[3] = (bf16)v.w;
      ((uint2*)xb)[i4] = p.u;
    }
    float (*tile)[65] = (float (*)[65])smem;
    const int rr = tid >> 6, c = tid & 63;  // rr 0..7
    for (int tj = 0; tj < 4; ++tj) {
      const int id = bid * 4 + tj;  // 0..1023 (4 mats x 16x16 64-tiles)
      const int mat = id >> 8;
      const float* src = mat == 0 ? Wq : mat == 1 ? Wk : mat == 2 ? Wv : Wo;
      bf16* dst = WT + (size_t)mat * 1048576;
      const int k0 = ((id >> 4) & 15) * 64, n0 = (id & 15) * 64;
      __syncthreads();  // protect previous tile's reads
#pragma unroll
      for (int i2 = 0; i2 < 8; ++i2) {
        const int r = i2 * 8 + rr;
        tile[r][c] = src[(size_t)(k0 + r) * 1024 + n0 + c];
      }
      __syncthreads();
#pragma unroll
      for (int i2 = 0; i2 < 8; ++i2) {
        const int r = i2 * 8 + rr;
        dst[(size_t)(n0 + r) * 1024 + k0 + c] = (bf16)tile[c][r];
      }
    }
  }
  gridbar(cnt, 256);

  // ---- phase 1: qkv (192 tiles of 256x256 over blocks 0..191) ----
  if (bid < 192) {
    bf16* As = (bf16*)smem;            // 64 KiB
    bf16* Bs = (bf16*)(smem + 65536);  // 64 KiB
    const int m0 = (bid / 12) * 256, n0 = (bid % 12) * 256;
    const int wm = wave >> 2, wn = wave & 3;

    f32x4 acc[8][4];
    const f32x4 zero = {0.f, 0.f, 0.f, 0.f};
#pragma unroll
    for (int i = 0; i < 8; ++i)
#pragma unroll
      for (int j = 0; j < 4; ++j) acc[i][j] = zero;

    stage_half(xb, m0, 0, (char*)As, 0, wave, lane);
    stage_half(WT, n0, 0, (char*)Bs, 0, wave, lane);
    stage_half(xb, m0 + 128, 0, (char*)As, 1, wave, lane);
    stage_half(WT, n0 + 128, 0, (char*)Bs, 1, wave, lane);
    stage_half(xb, m0, 64, (char*)As, 2, wave, lane);
    stage_half(WT, n0 + 128, 64, (char*)Bs, 3, wave, lane);
    asm volatile("s_waitcnt vmcnt(4)" ::: "memory");
    __builtin_amdgcn_s_barrier();

    for (int j = 0; j < 7; ++j)
      qkv_iter<true>(j * 128, xb, WT, m0, n0, As, Bs, acc, wave, lane, wm, wn, quad, l16);
    qkv_iter<false>(896, xb, WT, m0, n0, As, Bs, acc, wave, lane, wm, wn, quad, l16);

    // epilogue: bias, fold softmax scale into Q, scatter to [B,H,S,HD]
#pragma unroll
    for (int MQ = 0; MQ < 2; ++MQ)
#pragma unroll
      for (int mf = 0; mf < 4; ++mf)
#pragma unroll
        for (int NQ = 0; NQ < 2; ++NQ)
#pragma unroll
          for (int nf = 0; nf < 2; ++nf) {
            const int n = n0 + NQ * 128 + wn * 32 + nf * 16 + l16;  // 0..3071
            const int sel = n >> 10, d = n & 1023;
            const float bias = (sel == 0 ? bq : sel == 1 ? bk : bv)[d];
            bf16* dst = (sel == 0 ? Qd : sel == 1 ? Kd : Vd);
            const float scl = (sel == 0) ? 0.125f : 1.f;
            const int h = d >> 6, hd = d & 63;
#pragma unroll
            for (int r = 0; r < 4; ++r) {
              const int token = m0 + MQ * 128 + wm * 64 + mf * 16 + quad * 4 + r;
              const int bb = token >> 11, s = token & 2047;
              const float v = (acc[MQ * 4 + mf][NQ * 2 + nf][r] + bias) * scl;
              dst[((((size_t)bb * 16 + h) * 2048 + s) << 6) + hd] = (bf16)v;
            }
          }
  }
  gridbar(cnt, 512);

  // ---- phase 2: attn (512 jobs of 128-query tiles; 2 per block, same qt) ----
  {
    bf16* Ks = (bf16*)smem;            // 16384 B (128 keys x 64)
    bf16* Vt = (bf16*)(smem + 16384);  // 17408 B (64 x 136)
    bf16* Ps = (bf16*)(smem + 33792);  // 34816 B (8 waves x 16 x 136)
    attn_job(bid, Qd, Kd, Vd, Ao, Ks, Vt, Ps);
    attn_job(bid + 256, Qd, Kd, Vd, Ao, Ks, Vt, Ps);
  }
  gridbar(cnt, 768);

  // ---- phase 3: out GEMM (256 tiles of 128x128, 1 per block) ----
  {
    bf16* As = (bf16*)smem;            // 16 KiB (128 x 64)
    bf16* Bs = (bf16*)(smem + 16384);  // 16 KiB
    const bf16* WoT = WT + (size_t)3 * 1048576;
    const int m0 = (bid >> 3) * 128, n0 = (bid & 7) * 128;
    const int wm = wave >> 2, wn = wave & 3;

    f32x4 acc[4][2];
    const f32x4 zero = {0.f, 0.f, 0.f, 0.f};
#pragma unroll
    for (int i = 0; i < 4; ++i)
#pragma unroll
      for (int j = 0; j < 2; ++j) acc[i][j] = zero;

    for (int k0 = 0; k0 < 1024; k0 += 64) {
#pragma unroll
      for (int i = 0; i < 2; ++i) {
        const int chunk = i * 512 + wave * 64 + lane;
        const int row = chunk >> 3, cg = (chunk & 7) ^ (row & 7);
        ldsdma16(Ao + (size_t)(m0 + row) * 1024 + k0 + cg * 8,
                 (char*)As + (size_t)(i * 512 + wave * 64) * 16);
      }
#pragma unroll
      for (int i = 0; i < 2; ++i) {
        const int chunk = i * 512 + wave * 64 + lane;
        const int row = chunk >> 3, cg = (chunk & 7) ^ (row & 7);
        ldsdma16(WoT + (size_t)(n0 + row) * 1024 + k0 + cg * 8,
                 (char*)Bs + (size_t)(i * 512 + wave * 64) * 16);
      }
      __syncthreads();
      bf16x8 aF[4][2], bF[2][2];
      ld_frag4(As, 0, wm * 64, quad, l16, aF);
      ld_frag2(Bs, 0, wn * 32, quad, l16, bF);
      __builtin_amdgcn_s_setprio(1);
#pragma unroll
      for (int mf = 0; mf < 4; ++mf)
#pragma unroll
        for (int nf = 0; nf < 2; ++nf)
#pragma unroll
          for (int kk = 0; kk < 2; ++kk)
            acc[mf][nf] = MFMA16(aF[mf][kk], bF[nf][kk], acc[mf][nf]);
      __builtin_amdgcn_s_setprio(0);
      __syncthreads();
    }

#pragma unroll
    for (int nf = 0; nf < 2; ++nf) {
      const int n = n0 + wn * 32 + nf * 16 + l16;
      const float bias = bo[n];
#pragma unroll
      for (int mf = 0; mf < 4; ++mf) {
#pragma unroll
        for (int r = 0; r < 4; ++r) {
          const int token = m0 + wm * 64 + mf * 16 + quad * 4 + r;
          out[(size_t)token * 1024 + n] = acc[mf][nf][r] + bias;
        }
      }
    }
  }
}

// ---------------------------------------------------------------------------
extern "C" void kernel_launch(void* const* d_in, const int* in_sizes, int n_in,
                              void* d_out, int out_size, void* d_ws, size_t ws_size,
                              hipStream_t stream) {
  const float* x  = (const float*)d_in[0];
  const float* Wq = (const float*)d_in[1];
  const float* bq = (const float*)d_in[2];
  const float* Wk = (const float*)d_in[3];
  const float* bk = (const float*)d_in[4];
  const float* Wv = (const float*)d_in[5];
  const float* bv = (const float*)d_in[6];
  const float* Wo = (const float*)d_in[7];
  const float* bo = (const float*)d_in[8];
  float* outp = (float*)d_out;

  char* ws = (char*)d_ws;
  bf16* xb = (bf16*)(ws);                      //  8 MB  x bf16
  bf16* WT = (bf16*)(ws + ((size_t)8 << 20));  //  8 MB  WqT|WkT|WvT|WoT bf16 [n][k]
  bf16* Qd = (bf16*)(ws + ((size_t)16 << 20)); //  8 MB  [B,H,S,HD]
  bf16* Kd = (bf16*)(ws + ((size_t)24 << 20)); //  8 MB
  bf16* Vd = (bf16*)(ws + ((size_t)32 << 20)); //  8 MB
  bf16* Ao = (bf16*)(ws + ((size_t)40 << 20)); //  8 MB  [B,S,DIM]
  unsigned* cnt = (unsigned*)(ws + ((size_t)48 << 20));

  (void)hipFuncSetAttribute((const void*)mega,
                            hipFuncAttributeMaxDynamicSharedMemorySize, 131072);
  (void)hipMemsetAsync(cnt, 0, 256, stream);

  void* kargs[] = {(void*)&x,  (void*)&Wq, (void*)&Wk, (void*)&Wv, (void*)&Wo,
                   (void*)&bq, (void*)&bk, (void*)&bv, (void*)&bo,
                   (void*)&xb, (void*)&WT, (void*)&Qd, (void*)&Kd, (void*)&Vd,
                   (void*)&Ao, (void*)&outp, (void*)&cnt};
  hipError_t err = hipLaunchCooperativeKernel((const void*)mega, dim3(256), dim3(512),
                                              kargs, 131072, stream);
  if (err != hipSuccess) {
    // co-residency still guaranteed: 128 KiB LDS -> exactly 1 block/CU, 256 blocks
    mega<<<dim3(256), dim3(512), 131072, stream>>>(x, Wq, Wk, Wv, Wo, bq, bk, bv, bo,
                                                   xb, WT, Qd, Kd, Vd, Ao, outp, cnt);
  }
}

// Round 4
// 208.930 us; speedup vs baseline: 1.2799x; 1.2799x over previous
//
#include <hip/hip_runtime.h>
#include <stdint.h>

typedef __bf16 bf16;
typedef __bf16 bf16x8 __attribute__((ext_vector_type(8)));
typedef float f32x4 __attribute__((ext_vector_type(4)));

#define MFMA16(a, b, c) __builtin_amdgcn_mfma_f32_16x16x32_bf16((a), (b), (c), 0, 0, 0)

// async global->LDS DMA, 16B per lane. LDS dest must be wave-uniform; HW writes base + lane*16.
__device__ __forceinline__ void ldsdma16(const void* g, void* l) {
  __builtin_amdgcn_global_load_lds((const __attribute__((address_space(1))) void*)g,
                                   (__attribute__((address_space(3))) void*)l, 16, 0, 0);
}

// ---------------------------------------------------------------------------
// Grid barrier across 256 co-resident blocks (1 block/CU forced by LDS size;
// plain launch). Counter zeroed by hipMemsetAsync before launch.
// ---------------------------------------------------------------------------
__device__ __forceinline__ void gridbar(unsigned* cnt, unsigned target) {
  __syncthreads();  // all waves drain vmcnt(0) -> block's stores are in L2
  if (threadIdx.x == 0) {
    __hip_atomic_fetch_add(cnt, 1u, __ATOMIC_ACQ_REL, __HIP_MEMORY_SCOPE_AGENT);
    while (__hip_atomic_load(cnt, __ATOMIC_RELAXED, __HIP_MEMORY_SCOPE_AGENT) < target)
      __builtin_amdgcn_s_sleep(8);
    (void)__hip_atomic_load(cnt, __ATOMIC_ACQUIRE, __HIP_MEMORY_SCOPE_AGENT);
  }
  __syncthreads();
}

// ===========================================================================
// QKV 8-phase helpers (256x256 tile, BK=64, 8 waves 2Mx4N) — verified R1-R3.
// ===========================================================================
__device__ __forceinline__ void stage_half(const bf16* __restrict__ src, int rowbase,
                                           int koff, char* lds, int bufq, int wave,
                                           int lane) {
#pragma unroll
  for (int i = 0; i < 2; ++i) {
    int chunk = i * 512 + wave * 64 + lane;  // 16B chunks, 8 per 64-col row
    int row = chunk >> 3;
    int cg = (chunk & 7) ^ (row & 7);        // pre-swizzled source column group
    ldsdma16(src + (size_t)(rowbase + row) * 1024 + koff + cg * 8,
             lds + bufq * 16384 + (i * 512 + wave * 64) * 16);
  }
}

__device__ __forceinline__ void ld_frag4(const bf16* lds, int bufq, int rbase, int quad,
                                         int l16, bf16x8 (&d)[4][2]) {
  const bf16x8* hb = (const bf16x8*)lds + bufq * 1024;
#pragma unroll
  for (int mf = 0; mf < 4; ++mf) {
    int row = rbase + mf * 16 + l16;
#pragma unroll
    for (int kk = 0; kk < 2; ++kk)
      d[mf][kk] = hb[row * 8 + ((kk * 4 + quad) ^ (row & 7))];
  }
}

__device__ __forceinline__ void ld_frag2(const bf16* lds, int bufq, int rbase, int quad,
                                         int l16, bf16x8 (&d)[2][2]) {
  const bf16x8* hb = (const bf16x8*)lds + bufq * 1024;
#pragma unroll
  for (int nf = 0; nf < 2; ++nf) {
    int row = rbase + nf * 16 + l16;
#pragma unroll
    for (int kk = 0; kk < 2; ++kk)
      d[nf][kk] = hb[row * 8 + ((kk * 4 + quad) ^ (row & 7))];
  }
}

template <int MQ, int NQ>
__device__ __forceinline__ void mma_quad(f32x4 (&acc)[8][4], const bf16x8 (&a)[4][2],
                                         const bf16x8 (&b)[2][2]) {
  __builtin_amdgcn_s_setprio(1);
#pragma unroll
  for (int mf = 0; mf < 4; ++mf)
#pragma unroll
    for (int nf = 0; nf < 2; ++nf)
#pragma unroll
      for (int kk = 0; kk < 2; ++kk)
        acc[MQ * 4 + mf][NQ * 2 + nf] =
            MFMA16(a[mf][kk], b[nf][kk], acc[MQ * 4 + mf][NQ * 2 + nf]);
  __builtin_amdgcn_s_setprio(0);
}

#define QBAR1() { __builtin_amdgcn_s_barrier(); \
                  asm volatile("s_waitcnt lgkmcnt(0)" ::: "memory"); }
#define QBAR2() { __builtin_amdgcn_s_barrier(); }

template <bool PRE>
__device__ __forceinline__ void qkv_iter(int k0, const bf16* __restrict__ xb,
                                         const bf16* __restrict__ BT, int m0, int n0,
                                         bf16* As, bf16* Bs, f32x4 (&acc)[8][4], int wave,
                                         int lane, int wm, int wn, int quad, int l16) {
  bf16x8 aF[4][2], b0F[2][2], b1F[2][2];
  // P1: quad (mq0,nq0) of tile a; stage A1(b)
  ld_frag4(As, 0, wm * 64, quad, l16, aF);
  ld_frag2(Bs, 0, wn * 32, quad, l16, b0F);
  stage_half(xb, m0 + 128, k0 + 64, (char*)As, 3, wave, lane);
  QBAR1(); mma_quad<0, 0>(acc, aF, b0F); QBAR2();
  // P2: (mq0,nq1), reuse aF; stage B0(b)
  ld_frag2(Bs, 1, wn * 32, quad, l16, b1F);
  stage_half(BT, n0, k0 + 64, (char*)Bs, 2, wave, lane);
  QBAR1(); mma_quad<0, 1>(acc, aF, b1F); QBAR2();
  // P3: (mq1,nq1); stage A0(a+2)
  ld_frag4(As, 1, wm * 64, quad, l16, aF);
  if (PRE) stage_half(xb, m0, k0 + 128, (char*)As, 0, wave, lane);
  QBAR1(); mma_quad<1, 1>(acc, aF, b1F); QBAR2();
  // P4: (mq1,nq0), reuse aF,b0F; stage B1(a+2); vmcnt gate for tile b
  if (PRE) stage_half(BT, n0 + 128, k0 + 128, (char*)Bs, 1, wave, lane);
  QBAR1(); mma_quad<1, 0>(acc, aF, b0F);
  if (PRE) { asm volatile("s_waitcnt vmcnt(4)" ::: "memory"); }
  else     { asm volatile("s_waitcnt vmcnt(0)" ::: "memory"); }
  QBAR2();
  // P5: tile b (mq0,nq0); stage A1(a+2)
  ld_frag4(As, 2, wm * 64, quad, l16, aF);
  ld_frag2(Bs, 2, wn * 32, quad, l16, b0F);
  if (PRE) stage_half(xb, m0 + 128, k0 + 128, (char*)As, 1, wave, lane);
  QBAR1(); mma_quad<0, 0>(acc, aF, b0F); QBAR2();
  // P6: (mq0,nq1); stage B0(a+2)
  ld_frag2(Bs, 3, wn * 32, quad, l16, b1F);
  if (PRE) stage_half(BT, n0, k0 + 128, (char*)Bs, 0, wave, lane);
  QBAR1(); mma_quad<0, 1>(acc, aF, b1F); QBAR2();
  // P7: (mq1,nq1); stage A0(b+2)
  ld_frag4(As, 3, wm * 64, quad, l16, aF);
  if (PRE) stage_half(xb, m0, k0 + 192, (char*)As, 2, wave, lane);
  QBAR1(); mma_quad<1, 1>(acc, aF, b1F); QBAR2();
  // P8: (mq1,nq0); stage B1(b+2); vmcnt gate for tile a+2
  if (PRE) stage_half(BT, n0 + 128, k0 + 192, (char*)Bs, 3, wave, lane);
  QBAR1(); mma_quad<1, 0>(acc, aF, b0F);
  if (PRE) { asm volatile("s_waitcnt vmcnt(4)" ::: "memory"); }
  QBAR2();
}

// ===========================================================================
// FRONT: prep (cast x, transpose-cast W) -> gridbar -> qkv GEMM.
// 256 blocks x 512 threads, 128 KiB dynamic LDS (1 block/CU, co-resident).
// ===========================================================================
__global__ void __launch_bounds__(512, 2)
front(const float* __restrict__ x, const float* __restrict__ Wq,
      const float* __restrict__ Wk, const float* __restrict__ Wv,
      const float* __restrict__ Wo, const float* __restrict__ bq,
      const float* __restrict__ bk, const float* __restrict__ bv,
      bf16* __restrict__ xb, bf16* __restrict__ WT, bf16* __restrict__ Qd,
      bf16* __restrict__ Kd, bf16* __restrict__ Vd, unsigned* cnt) {
  extern __shared__ char smem[];
  const int tid = threadIdx.x, lane = tid & 63, wave = tid >> 6;
  const int quad = lane >> 4, l16 = lane & 15;
  const int bid = blockIdx.x;

  // ---- prep: cast x; transpose-cast W ----
  {
    const int gt = bid * 512 + tid;
#pragma unroll
    for (int it = 0; it < 8; ++it) {
      const int i4 = it * 131072 + gt;  // float4 index, 1M total
      const float4 v = ((const float4*)x)[i4];
      union { bf16 h[4]; uint2 u; } p;
      p.h[0] = (bf16)v.x; p.h[1] = (bf16)v.y; p.h[2] = (bf16)v.z; p.h[3] = (bf16)v.w;
      ((uint2*)xb)[i4] = p.u;
    }
    float (*tile)[65] = (float (*)[65])smem;
    const int rr = tid >> 6, c = tid & 63;  // rr 0..7
    for (int tj = 0; tj < 4; ++tj) {
      const int id = bid * 4 + tj;  // 0..1023 (4 mats x 16x16 64-tiles)
      const int mat = id >> 8;
      const float* src = mat == 0 ? Wq : mat == 1 ? Wk : mat == 2 ? Wv : Wo;
      bf16* dst = WT + (size_t)mat * 1048576;
      const int k0 = ((id >> 4) & 15) * 64, n0 = (id & 15) * 64;
      __syncthreads();  // protect previous tile's reads
#pragma unroll
      for (int i2 = 0; i2 < 8; ++i2) {
        const int r = i2 * 8 + rr;
        tile[r][c] = src[(size_t)(k0 + r) * 1024 + n0 + c];
      }
      __syncthreads();
#pragma unroll
      for (int i2 = 0; i2 < 8; ++i2) {
        const int r = i2 * 8 + rr;
        dst[(size_t)(n0 + r) * 1024 + k0 + c] = (bf16)tile[c][r];
      }
    }
  }
  gridbar(cnt, 256);

  // ---- qkv: 192 tiles of 256x256 over blocks 0..191 ----
  if (bid >= 192) return;
  bf16* As = (bf16*)smem;            // 64 KiB
  bf16* Bs = (bf16*)(smem + 65536);  // 64 KiB
  const int m0 = (bid / 12) * 256, n0 = (bid % 12) * 256;
  const int wm = wave >> 2, wn = wave & 3;

  f32x4 acc[8][4];
  const f32x4 zero = {0.f, 0.f, 0.f, 0.f};
#pragma unroll
  for (int i = 0; i < 8; ++i)
#pragma unroll
    for (int j = 0; j < 4; ++j) acc[i][j] = zero;

  stage_half(xb, m0, 0, (char*)As, 0, wave, lane);
  stage_half(WT, n0, 0, (char*)Bs, 0, wave, lane);
  stage_half(xb, m0 + 128, 0, (char*)As, 1, wave, lane);
  stage_half(WT, n0 + 128, 0, (char*)Bs, 1, wave, lane);
  stage_half(xb, m0, 64, (char*)As, 2, wave, lane);
  stage_half(WT, n0 + 128, 64, (char*)Bs, 3, wave, lane);
  asm volatile("s_waitcnt vmcnt(4)" ::: "memory");
  __builtin_amdgcn_s_barrier();

  for (int j = 0; j < 7; ++j)
    qkv_iter<true>(j * 128, xb, WT, m0, n0, As, Bs, acc, wave, lane, wm, wn, quad, l16);
  qkv_iter<false>(896, xb, WT, m0, n0, As, Bs, acc, wave, lane, wm, wn, quad, l16);

  // epilogue: bias, fold softmax scale into Q, scatter to [B,H,S,HD]
#pragma unroll
  for (int MQ = 0; MQ < 2; ++MQ)
#pragma unroll
    for (int mf = 0; mf < 4; ++mf)
#pragma unroll
      for (int NQ = 0; NQ < 2; ++NQ)
#pragma unroll
        for (int nf = 0; nf < 2; ++nf) {
          const int n = n0 + NQ * 128 + wn * 32 + nf * 16 + l16;  // 0..3071
          const int sel = n >> 10, d = n & 1023;
          const float bias = (sel == 0 ? bq : sel == 1 ? bk : bv)[d];
          bf16* dst = (sel == 0 ? Qd : sel == 1 ? Kd : Vd);
          const float scl = (sel == 0) ? 0.125f : 1.f;
          const int h = d >> 6, hd = d & 63;
#pragma unroll
          for (int r = 0; r < 4; ++r) {
            const int token = m0 + MQ * 128 + wm * 64 + mf * 16 + quad * 4 + r;
            const int bb = token >> 11, s = token & 2047;
            const float v = (acc[MQ * 4 + mf][NQ * 2 + nf][r] + bias) * scl;
            dst[((((size_t)bb * 16 + h) * 2048 + s) << 6) + hd] = (bf16)v;
          }
        }
}

// ===========================================================================
// Attention phase (8-wave / 128-query-tile) — verified R3.
// ===========================================================================
template <int MODE>
__device__ __forceinline__ void attn_phase8(int start, const bf16* __restrict__ Kb,
                                            const bf16* __restrict__ Vb, bf16* Ks, bf16* Vt,
                                            bf16* Psw, const bf16x8 qa0, const bf16x8 qa1,
                                            int i0, float (&mrow)[4], float (&lrow)[4],
                                            f32x4 (&oacc)[4]) {
  const int tid = threadIdx.x, lane = tid & 63, wave = tid >> 6;
  const int quad = lane >> 4, l16 = lane & 15;
  const f32x4 zero = {0.f, 0.f, 0.f, 0.f};

  __syncthreads();  // previous phase's Ks/Vt reads done
#pragma unroll
  for (int c = 0; c < 2; ++c) {
    int chunk = c * 512 + wave * 64 + lane;
    int row = chunk >> 3;
    int cg = (chunk & 7) ^ (row & 7);
    ldsdma16(Kb + (size_t)(start + row) * 64 + cg * 8,
             (char*)Ks + (size_t)(c * 512 + wave * 64) * 16);
  }
  {
    const int key = tid >> 2, hc = (tid & 3) * 16;
    const bf16* vp = Vb + (size_t)(start + key) * 64 + hc;
    bf16x8 v0 = ((const bf16x8*)vp)[0], v1 = ((const bf16x8*)vp)[1];
#pragma unroll
    for (int i = 0; i < 8; ++i) Vt[(hc + i) * 136 + key] = v0[i];
#pragma unroll
    for (int i = 0; i < 8; ++i) Vt[(hc + 8 + i) * 136 + key] = v1[i];
  }
  __syncthreads();

  f32x4 sc[8];
  __builtin_amdgcn_s_setprio(1);
#pragma unroll
  for (int nt = 0; nt < 8; ++nt) {
    int key = nt * 16 + l16;
    bf16x8 kb0 = ((const bf16x8*)Ks)[key * 8 + ((0 * 4 + quad) ^ (key & 7))];
    bf16x8 kb1 = ((const bf16x8*)Ks)[key * 8 + ((1 * 4 + quad) ^ (key & 7))];
    f32x4 s = zero;
    s = MFMA16(qa0, kb0, s);
    s = MFMA16(qa1, kb1, s);
    sc[nt] = s;
  }
  __builtin_amdgcn_s_setprio(0);

  float alpha[4];
#pragma unroll
  for (int r = 0; r < 4; ++r) {
    const int i = i0 + r;
    float mx = -1e30f;
#pragma unroll
    for (int nt = 0; nt < 8; ++nt) {
      float s = sc[nt][r];
      if (MODE == 1) {
        const bool valid = (start + nt * 16 + l16 + 255 >= i);
        s = valid ? s : -1e30f;
        sc[nt][r] = s;
      } else if (MODE == 2) {
        const bool valid = (start + nt * 16 + l16 <= i);
        s = valid ? s : -1e30f;
        sc[nt][r] = s;
      }
      mx = fmaxf(mx, s);
    }
#pragma unroll
    for (int m = 8; m >= 1; m >>= 1) mx = fmaxf(mx, __shfl_xor(mx, m, 64));
    const float mnew = fmaxf(mrow[r], mx);
    alpha[r] = __expf(mrow[r] - mnew);
    mrow[r] = mnew;
    float rs = 0.f;
#pragma unroll
    for (int nt = 0; nt < 8; ++nt) {
      const float p = __expf(sc[nt][r] - mnew);
      sc[nt][r] = p;
      rs += p;
    }
#pragma unroll
    for (int m = 8; m >= 1; m >>= 1) rs += __shfl_xor(rs, m, 64);
    lrow[r] = lrow[r] * alpha[r] + rs;
  }

#pragma unroll
  for (int nt = 0; nt < 8; ++nt)
#pragma unroll
    for (int r = 0; r < 4; ++r)
      Psw[(quad * 4 + r) * 136 + nt * 16 + l16] = (bf16)sc[nt][r];
  asm volatile("s_waitcnt lgkmcnt(0)" ::: "memory");  // same-wave LDS RAW
  bf16x8 pa[4];
#pragma unroll
  for (int ks = 0; ks < 4; ++ks)
    pa[ks] = ((const bf16x8*)Psw)[l16 * 17 + ks * 4 + quad];

  __builtin_amdgcn_s_setprio(1);
#pragma unroll
  for (int ht = 0; ht < 4; ++ht) {
    f32x4 o = oacc[ht];
#pragma unroll
    for (int r = 0; r < 4; ++r) o[r] *= alpha[r];
#pragma unroll
    for (int ks = 0; ks < 4; ++ks) {
      bf16x8 vb = ((const bf16x8*)Vt)[(ht * 16 + l16) * 17 + ks * 4 + quad];
      o = MFMA16(pa[ks], vb, o);
    }
    oacc[ht] = o;
  }
  __builtin_amdgcn_s_setprio(0);
}

__device__ __forceinline__ void attn_job(int job, const bf16* __restrict__ Q,
                                         const bf16* __restrict__ K,
                                         const bf16* __restrict__ V, bf16* __restrict__ Ao,
                                         bf16* Ks, bf16* Vt, bf16* Ps) {
  const int tid = threadIdx.x, lane = tid & 63, wave = tid >> 6;
  const int quad = lane >> 4, l16 = lane & 15;
  const int qt = job & 15, h = (job >> 4) & 15, b = job >> 8;
  const int q0 = qt * 128;
  const size_t base = ((size_t)(b * 16 + h)) * 2048 * 64;
  const bf16* Qb = Q + base + (size_t)q0 * 64;
  const bf16* Kb = K + base;
  const bf16* Vb = V + base;

  const bf16* qrow = Qb + (size_t)(wave * 16 + l16) * 64 + quad * 8;
  const bf16x8 qa0 = *(const bf16x8*)qrow;
  const bf16x8 qa1 = *(const bf16x8*)(qrow + 32);

  float mrow[4], lrow[4];
  f32x4 oacc[4];
  const f32x4 zero = {0.f, 0.f, 0.f, 0.f};
#pragma unroll
  for (int r = 0; r < 4; ++r) { mrow[r] = -1e30f; lrow[r] = 0.f; }
#pragma unroll
  for (int t = 0; t < 4; ++t) oacc[t] = zero;

  const int i0 = q0 + wave * 16 + quad * 4;
  bf16* Psw = Ps + wave * (16 * 136);

  if (q0 >= 256)
    attn_phase8<1>(q0 - 256, Kb, Vb, Ks, Vt, Psw, qa0, qa1, i0, mrow, lrow, oacc);
  if (q0 >= 128)
    attn_phase8<0>(q0 - 128, Kb, Vb, Ks, Vt, Psw, qa0, qa1, i0, mrow, lrow, oacc);
  attn_phase8<2>(q0, Kb, Vb, Ks, Vt, Psw, qa0, qa1, i0, mrow, lrow, oacc);

#pragma unroll
  for (int r = 0; r < 4; ++r) {
    const float inv = 1.f / lrow[r];
    const int row = q0 + wave * 16 + quad * 4 + r;
    const size_t outb = ((size_t)(b * 2048 + row)) * 1024 + h * 64;
#pragma unroll
    for (int ht = 0; ht < 4; ++ht)
      Ao[outb + ht * 16 + l16] = (bf16)(oacc[ht][r] * inv);
  }
}

// ===========================================================================
// BACK: attn (2 jobs/block) -> gridbar -> out GEMM (128x128 tile, ring-2
// double-buffered BK=64 K-loop with counted vmcnt gates).
// 256 blocks x 512 threads, 68608 B dynamic LDS (1 block/CU, co-resident).
// ===========================================================================
__global__ void __launch_bounds__(512, 2)
back(const bf16* __restrict__ Qd, const bf16* __restrict__ Kd,
     const bf16* __restrict__ Vd, const bf16* __restrict__ WT,
     const float* __restrict__ bo, bf16* __restrict__ Ao, float* __restrict__ out,
     unsigned* cnt) {
  extern __shared__ char smem[];
  const int tid = threadIdx.x, lane = tid & 63, wave = tid >> 6;
  const int quad = lane >> 4, l16 = lane & 15;
  const int bid = blockIdx.x;

  // ---- attn: 512 jobs of 128-query tiles; 2 per block ----
  {
    bf16* Ks = (bf16*)smem;            // 16384 B (128 keys x 64)
    bf16* Vt = (bf16*)(smem + 16384);  // 17408 B (64 x 136)
    bf16* Ps = (bf16*)(smem + 33792);  // 34816 B (8 waves x 16 x 136)
    attn_job(bid, Qd, Kd, Vd, Ao, Ks, Vt, Ps);
    attn_job(bid + 256, Qd, Kd, Vd, Ao, Ks, Vt, Ps);
  }
  gridbar(cnt, 256);

  // ---- out GEMM: 256 tiles of 128x128, 1 per block, ring-2 pipelined ----
  {
    bf16* As = (bf16*)smem;            // 2 x 16 KiB
    bf16* Bs = (bf16*)(smem + 32768);  // 2 x 16 KiB
    const bf16* WoT = WT + (size_t)3 * 1048576;
    const int m0 = (bid >> 3) * 128, n0 = (bid & 7) * 128;
    const int wm = wave >> 2, wn = wave & 3;

    f32x4 acc[4][2];
    const f32x4 zero = {0.f, 0.f, 0.f, 0.f};
#pragma unroll
    for (int i = 0; i < 4; ++i)
#pragma unroll
      for (int j = 0; j < 2; ++j) acc[i][j] = zero;

    // stage_tile(t -> buf t&1): A and B, 2 chunks each per thread
#define OUT_STAGE(t)                                                                  \
    {                                                                                 \
      const int _buf = (t) & 1;                                                       \
      const int _k0 = (t) * 64;                                                       \
      _Pragma("unroll")                                                               \
      for (int _i = 0; _i < 2; ++_i) {                                                \
        const int chunk = _i * 512 + tid;                                             \
        const int row = chunk >> 3, cg = (chunk & 7) ^ (row & 7);                     \
        ldsdma16(Ao + (size_t)(m0 + row) * 1024 + _k0 + cg * 8,                       \
                 (char*)As + (size_t)_buf * 16384 + (_i * 512 + wave * 64) * 16);     \
      }                                                                               \
      _Pragma("unroll")                                                               \
      for (int _i = 0; _i < 2; ++_i) {                                                \
        const int chunk = _i * 512 + tid;                                             \
        const int row = chunk >> 3, cg = (chunk & 7) ^ (row & 7);                     \
        ldsdma16(WoT + (size_t)(n0 + row) * 1024 + _k0 + cg * 8,                      \
                 (char*)Bs + (size_t)_buf * 16384 + (_i * 512 + wave * 64) * 16);     \
      }                                                                               \
    }

    OUT_STAGE(0);
    for (int t = 0; t < 16; ++t) {
      if (t < 15) {
        OUT_STAGE(t + 1);
        asm volatile("s_waitcnt vmcnt(4)" ::: "memory");  // tile t's 4 loads landed
      } else {
        asm volatile("s_waitcnt vmcnt(0)" ::: "memory");
      }
      __builtin_amdgcn_s_barrier();  // all waves' tile-t loads landed
      bf16x8 aF[4][2], bF[2][2];
      ld_frag4(As, t & 1, wm * 64, quad, l16, aF);
      ld_frag2(Bs, t & 1, wn * 32, quad, l16, bF);
      __builtin_amdgcn_s_setprio(1);
#pragma unroll
      for (int mf = 0; mf < 4; ++mf)
#pragma unroll
        for (int nf = 0; nf < 2; ++nf)
#pragma unroll
          for (int kk = 0; kk < 2; ++kk)
            acc[mf][nf] = MFMA16(aF[mf][kk], bF[nf][kk], acc[mf][nf]);
      __builtin_amdgcn_s_setprio(0);
      __builtin_amdgcn_s_barrier();  // frag reads done before buf reuse
    }
#undef OUT_STAGE

#pragma unroll
    for (int nf = 0; nf < 2; ++nf) {
      const int n = n0 + wn * 32 + nf * 16 + l16;
      const float bias = bo[n];
#pragma unroll
      for (int mf = 0; mf < 4; ++mf) {
#pragma unroll
        for (int r = 0; r < 4; ++r) {
          const int token = m0 + wm * 64 + mf * 16 + quad * 4 + r;
          out[(size_t)token * 1024 + n] = acc[mf][nf][r] + bias;
        }
      }
    }
  }
}

// ---------------------------------------------------------------------------
extern "C" void kernel_launch(void* const* d_in, const int* in_sizes, int n_in,
                              void* d_out, int out_size, void* d_ws, size_t ws_size,
                              hipStream_t stream) {
  const float* x  = (const float*)d_in[0];
  const float* Wq = (const float*)d_in[1];
  const float* bq = (const float*)d_in[2];
  const float* Wk = (const float*)d_in[3];
  const float* bk = (const float*)d_in[4];
  const float* Wv = (const float*)d_in[5];
  const float* bv = (const float*)d_in[6];
  const float* Wo = (const float*)d_in[7];
  const float* bo = (const float*)d_in[8];
  float* outp = (float*)d_out;

  char* ws = (char*)d_ws;
  bf16* xb = (bf16*)(ws);                      //  8 MB  x bf16
  bf16* WT = (bf16*)(ws + ((size_t)8 << 20));  //  8 MB  WqT|WkT|WvT|WoT bf16 [n][k]
  bf16* Qd = (bf16*)(ws + ((size_t)16 << 20)); //  8 MB  [B,H,S,HD]
  bf16* Kd = (bf16*)(ws + ((size_t)24 << 20)); //  8 MB
  bf16* Vd = (bf16*)(ws + ((size_t)32 << 20)); //  8 MB
  bf16* Ao = (bf16*)(ws + ((size_t)40 << 20)); //  8 MB  [B,S,DIM]
  unsigned* cntF = (unsigned*)(ws + ((size_t)48 << 20));
  unsigned* cntB = cntF + 32;  // separate cacheline

  (void)hipFuncSetAttribute((const void*)front,
                            hipFuncAttributeMaxDynamicSharedMemorySize, 131072);
  (void)hipFuncSetAttribute((const void*)back,
                            hipFuncAttributeMaxDynamicSharedMemorySize, 68608);
  (void)hipMemsetAsync(cntF, 0, 256, stream);

  front<<<dim3(256), dim3(512), 131072, stream>>>(x, Wq, Wk, Wv, Wo, bq, bk, bv,
                                                  xb, WT, Qd, Kd, Vd, cntF);
  back<<<dim3(256), dim3(512), 68608, stream>>>(Qd, Kd, Vd, WT, bo, Ao, outp, cntB);
}

// Round 6
// 176.174 us; speedup vs baseline: 1.5178x; 1.1859x over previous
//
#include <hip/hip_runtime.h>
#include <stdint.h>

typedef __bf16 bf16;
typedef __bf16 bf16x8 __attribute__((ext_vector_type(8)));
typedef float f32x4 __attribute__((ext_vector_type(4)));

#define MFMA16(a, b, c) __builtin_amdgcn_mfma_f32_16x16x32_bf16((a), (b), (c), 0, 0, 0)

// async global->LDS DMA, 16B per lane. LDS dest must be wave-uniform; HW writes base + lane*16.
__device__ __forceinline__ void ldsdma16(const void* g, void* l) {
  __builtin_amdgcn_global_load_lds((const __attribute__((address_space(1))) void*)g,
                                   (__attribute__((address_space(3))) void*)l, 16, 0, 0);
}

// ---------------------------------------------------------------------------
// prep (merged): z==4 -> cast x fp32->bf16; z<4 -> transpose-cast W -> WT[n][k]
// ---------------------------------------------------------------------------
__global__ __launch_bounds__(256) void prep_kernel(const float* __restrict__ x,
                                                   const float* __restrict__ Wq,
                                                   const float* __restrict__ Wk,
                                                   const float* __restrict__ Wv,
                                                   const float* __restrict__ Wo,
                                                   bf16* __restrict__ xb,
                                                   bf16* __restrict__ WT) {
  __shared__ float tile[64][65];
  if (blockIdx.z == 4) {
    const int t = (blockIdx.y * 16 + blockIdx.x) * 256 + threadIdx.x;
#pragma unroll
    for (int i = 0; i < 16; ++i) {
      const int idx = (t + i * 65536) * 4;
      float4 v = *(const float4*)(x + idx);
      union { bf16 h[4]; uint2 u; } p;
      p.h[0] = (bf16)v.x; p.h[1] = (bf16)v.y; p.h[2] = (bf16)v.z; p.h[3] = (bf16)v.w;
      *(uint2*)(xb + idx) = p.u;
    }
    return;
  }
  const float* src = blockIdx.z == 0 ? Wq : blockIdx.z == 1 ? Wk : blockIdx.z == 2 ? Wv : Wo;
  bf16* dst = WT + (size_t)blockIdx.z * 1024 * 1024;
  const int k0 = blockIdx.y * 64, n0 = blockIdx.x * 64;
  const int rr = threadIdx.x >> 6, c = threadIdx.x & 63;
#pragma unroll
  for (int i = 0; i < 16; ++i) {
    int r = i * 4 + rr;
    tile[r][c] = src[(size_t)(k0 + r) * 1024 + n0 + c];
  }
  __syncthreads();
#pragma unroll
  for (int i = 0; i < 16; ++i) {
    int r = i * 4 + rr;
    dst[(size_t)(n0 + r) * 1024 + k0 + c] = (bf16)tile[c][r];
  }
}

// ---------------------------------------------------------------------------
// m97-structure GEMM mainloop for qkv: C = A[M,K] * BT[N,K]^T, BK=32,
// 4 waves 2x2, wave tile 64x64. XOR swizzle (c ^ ((row>>1)&3)) on 16B chunks.
// 16 KiB LDS -> 3-4 blocks/CU (latency hidden by TLP; measured equal to the
// 8-phase port at this shape, R2).
// ---------------------------------------------------------------------------
__device__ __forceinline__ void gemm_mainloop4(const bf16* __restrict__ A,
                                               const bf16* __restrict__ BT, int K,
                                               int m0, int n0, bf16* As, bf16* Bs,
                                               f32x4 (&acc)[4][4]) {
  const int tid = threadIdx.x;
  const int lane = tid & 63;
  const int wave = tid >> 6;
  const int wm = wave >> 1, wn = wave & 1;
  const int quad = lane >> 4, l16 = lane & 15;

  const f32x4 zero = {0.f, 0.f, 0.f, 0.f};
#pragma unroll
  for (int i = 0; i < 4; ++i)
#pragma unroll
    for (int j = 0; j < 4; ++j) acc[i][j] = zero;

  const int ch0 = wave * 128 + lane;
  for (int k0 = 0; k0 < K; k0 += 32) {
#pragma unroll
    for (int c = 0; c < 2; ++c) {
      int chunk = ch0 + c * 64;
      int row = chunk >> 2;
      int cg = (chunk & 3) ^ ((row >> 1) & 3);
      ldsdma16(A + (size_t)(m0 + row) * K + k0 + cg * 8,
               (char*)As + (size_t)(wave * 128 + c * 64) * 16);
      ldsdma16(BT + (size_t)(n0 + row) * K + k0 + cg * 8,
               (char*)Bs + (size_t)(wave * 128 + c * 64) * 16);
    }
    __syncthreads();
    bf16x8 af[4], bfv[4];
#pragma unroll
    for (int i = 0; i < 4; ++i) {
      int ra = wm * 64 + i * 16 + l16;
      af[i] = ((const bf16x8*)As)[ra * 4 + (quad ^ ((ra >> 1) & 3))];
      int rb = wn * 64 + i * 16 + l16;
      bfv[i] = ((const bf16x8*)Bs)[rb * 4 + (quad ^ ((rb >> 1) & 3))];
    }
#pragma unroll
    for (int i = 0; i < 4; ++i)
#pragma unroll
      for (int j = 0; j < 4; ++j) acc[i][j] = MFMA16(af[i], bfv[j], acc[i][j]);
    __syncthreads();
  }
}

// ---------------------------------------------------------------------------
// QKV GEMM: xb[4096,1024] @ Wqkv -> Q/K/V in [B,H,S,HD] bf16. Q gets *SCALE.
// ---------------------------------------------------------------------------
__global__ __launch_bounds__(256) void qkv_gemm(const bf16* __restrict__ xb,
                                                const bf16* __restrict__ WT,
                                                const float* __restrict__ bq,
                                                const float* __restrict__ bk,
                                                const float* __restrict__ bv,
                                                bf16* __restrict__ Qd,
                                                bf16* __restrict__ Kd,
                                                bf16* __restrict__ Vd) {
  __shared__ bf16 As[128 * 32] __attribute__((aligned(16)));
  __shared__ bf16 Bs[128 * 32] __attribute__((aligned(16)));
  f32x4 acc[4][4];
  const int m0 = blockIdx.y * 128, n0 = blockIdx.x * 128;
  gemm_mainloop4(xb, WT, 1024, m0, n0, As, Bs, acc);

  const int lane = threadIdx.x & 63, wave = threadIdx.x >> 6;
  const int wm = wave >> 1, wn = wave & 1;
  const int quad = lane >> 4, l16 = lane & 15;
#pragma unroll
  for (int j = 0; j < 4; ++j) {
    const int n = n0 + wn * 64 + j * 16 + l16;  // 0..3071
    const int sel = n >> 10, d = n & 1023;
    const float bias = (sel == 0 ? bq : sel == 1 ? bk : bv)[d];
    bf16* dst = (sel == 0 ? Qd : sel == 1 ? Kd : Vd);
    const float scl = (sel == 0) ? 0.125f : 1.f;  // fold softmax scale into Q
    const int h = d >> 6, hd = d & 63;
#pragma unroll
    for (int i = 0; i < 4; ++i) {
#pragma unroll
      for (int r = 0; r < 4; ++r) {
        const int token = m0 + wm * 64 + i * 16 + quad * 4 + r;
        const int bb = token >> 11, s = token & 2047;
        const float v = (acc[i][j][r] + bias) * scl;
        dst[((((size_t)bb * 16 + h) * 2048 + s) << 6) + hd] = (bf16)v;
      }
    }
  }
}

// ---------------------------------------------------------------------------
// Sliding-window attention v2 (latency-lean):
//  - K frags read DIRECT from global (L2-resident; every wave needs all keys,
//    LDS dedup not worth the barrier chain).
//  - V: global->regs (prefetched one phase ahead, T14) -> transposed LDS store
//    into double-buffered Vt. ONE raw s_barrier per phase.
//  - Q frags direct from global. Softmax/P-roundtrip/PV as verified in R1.
// Phases per 64-query tile: <=3 (128/128/64 keys). MODE: 0 none, 1 window, 2 causal.
// LDS 52 KiB -> 3 blocks/CU.
// ---------------------------------------------------------------------------
template <int NT>
__device__ __forceinline__ void loadv(const bf16* __restrict__ Vb, int start,
                                      bf16x8 (&vp)[4]) {
  const int tid = threadIdx.x;
  if (NT == 8) {
    const int key = tid >> 1, hc = (tid & 1) * 32;
    const bf16x8* p = (const bf16x8*)(Vb + (size_t)(start + key) * 64 + hc);
#pragma unroll
    for (int r = 0; r < 4; ++r) vp[r] = p[r];
  } else {
    const int key = tid >> 2, hc = (tid & 3) * 16;
    const bf16x8* p = (const bf16x8*)(Vb + (size_t)(start + key) * 64 + hc);
#pragma unroll
    for (int r = 0; r < 2; ++r) vp[r] = p[r];
  }
}

template <int NT, int MODE, int NNT>
__device__ __forceinline__ void attn_phase(int start, int nstart,
                                           const bf16* __restrict__ Kb,
                                           const bf16* __restrict__ Vb, bf16* Vtc,
                                           bf16* Psw, bf16x8 (&vp)[4], bf16x8 (&vn)[4],
                                           const bf16x8 qa0, const bf16x8 qa1, int i0,
                                           float (&mrow)[4], float (&lrow)[4],
                                           f32x4 (&oacc)[4]) {
  const int tid = threadIdx.x, lane = tid & 63;
  const int quad = lane >> 4, l16 = lane & 15;
  const f32x4 zero = {0.f, 0.f, 0.f, 0.f};

  // write prefetched V regs -> Vt[cur] (transpose scatter). Safe without a
  // leading barrier: dbuf + the single per-phase barrier make the other
  // buffer's readers provably done (see derivation in journal).
  if (NT == 8) {
    const int key = tid >> 1, hc = (tid & 1) * 32;
#pragma unroll
    for (int r2 = 0; r2 < 4; ++r2)
#pragma unroll
      for (int i = 0; i < 8; ++i) Vtc[(hc + r2 * 8 + i) * 136 + key] = vp[r2][i];
  } else {
    const int key = tid >> 2, hc = (tid & 3) * 16;
#pragma unroll
    for (int r2 = 0; r2 < 2; ++r2)
#pragma unroll
      for (int i = 0; i < 8; ++i) Vtc[(hc + r2 * 8 + i) * 136 + key] = vp[r2][i];
  }
  // T14: issue next phase's V loads now; they fly under this phase's compute.
  if (NNT > 0) loadv<NNT>(Vb, nstart, vn);

  asm volatile("s_waitcnt lgkmcnt(0)" ::: "memory");  // Vt writes visible
  __builtin_amdgcn_s_barrier();                       // raw: V-next loads stay in flight

  // scores S = Q K^T, K frags straight from global (scale folded into Q)
  f32x4 sc[NT];
#pragma unroll
  for (int nt = 0; nt < NT; ++nt) {
    const int key = nt * 16 + l16;
    const bf16* kp = Kb + (size_t)(start + key) * 64 + quad * 8;
    const bf16x8 kb0 = *(const bf16x8*)kp;
    const bf16x8 kb1 = *(const bf16x8*)(kp + 32);
    f32x4 s = zero;
    s = MFMA16(qa0, kb0, s);
    s = MFMA16(qa1, kb1, s);
    sc[nt] = s;
  }

  // mask + online softmax
  float alpha[4];
#pragma unroll
  for (int r = 0; r < 4; ++r) {
    const int i = i0 + r;
    float mx = -1e30f;
#pragma unroll
    for (int nt = 0; nt < NT; ++nt) {
      float s = sc[nt][r];
      if (MODE == 1) {
        const bool valid = (start + nt * 16 + l16 + 255 >= i);
        s = valid ? s : -1e30f;
        sc[nt][r] = s;
      } else if (MODE == 2) {
        const bool valid = (start + nt * 16 + l16 <= i);
        s = valid ? s : -1e30f;
        sc[nt][r] = s;
      }
      mx = fmaxf(mx, s);
    }
#pragma unroll
    for (int m = 8; m >= 1; m >>= 1) mx = fmaxf(mx, __shfl_xor(mx, m, 64));
    const float mnew = fmaxf(mrow[r], mx);
    alpha[r] = __expf(mrow[r] - mnew);
    mrow[r] = mnew;
    float rs = 0.f;
#pragma unroll
    for (int nt = 0; nt < NT; ++nt) {
      const float p = __expf(sc[nt][r] - mnew);
      sc[nt][r] = p;
      rs += p;
    }
#pragma unroll
    for (int m = 8; m >= 1; m >>= 1) rs += __shfl_xor(rs, m, 64);
    lrow[r] = lrow[r] * alpha[r] + rs;
  }

  // P: C-layout -> A-layout via per-wave LDS round-trip (bf16)
#pragma unroll
  for (int nt = 0; nt < NT; ++nt)
#pragma unroll
    for (int r = 0; r < 4; ++r)
      Psw[(quad * 4 + r) * 136 + nt * 16 + l16] = (bf16)sc[nt][r];
  asm volatile("s_waitcnt lgkmcnt(0)" ::: "memory");  // same-wave LDS RAW
  bf16x8 pa[NT / 2];
#pragma unroll
  for (int ks = 0; ks < NT / 2; ++ks)
    pa[ks] = ((const bf16x8*)Psw)[l16 * 17 + ks * 4 + quad];

  // O = O*alpha + P V
  __builtin_amdgcn_s_setprio(1);
#pragma unroll
  for (int ht = 0; ht < 4; ++ht) {
    f32x4 o = oacc[ht];
#pragma unroll
    for (int r = 0; r < 4; ++r) o[r] *= alpha[r];
#pragma unroll
    for (int ks = 0; ks < NT / 2; ++ks) {
      bf16x8 vb = ((const bf16x8*)Vtc)[(ht * 16 + l16) * 17 + ks * 4 + quad];
      o = MFMA16(pa[ks], vb, o);
    }
    oacc[ht] = o;
  }
  __builtin_amdgcn_s_setprio(0);
}

__global__ __launch_bounds__(256) void attn_kernel(const bf16* __restrict__ Q,
                                                   const bf16* __restrict__ K,
                                                   const bf16* __restrict__ V,
                                                   bf16* __restrict__ Ao) {
  __shared__ bf16 Vt[2][64 * 136] __attribute__((aligned(16)));  // [hd][key] dbuf
  __shared__ bf16 Ps[4][16 * 136] __attribute__((aligned(16)));  // per-wave P scratch

  const int tid = threadIdx.x, lane = tid & 63, wave = tid >> 6;
  const int quad = lane >> 4, l16 = lane & 15;
  const int qt = blockIdx.x, h = blockIdx.y, b = blockIdx.z;
  const int q0 = qt * 64;
  const size_t base = ((size_t)(b * 16 + h)) * 2048 * 64;
  const bf16* Qb = Q + base + (size_t)q0 * 64;
  const bf16* Kb = K + base;
  const bf16* Vb = V + base;

  // Q fragments straight from global (L2-resident, one-shot)
  const bf16* qrow = Qb + (size_t)(wave * 16 + l16) * 64 + quad * 8;
  const bf16x8 qa0 = *(const bf16x8*)qrow;
  const bf16x8 qa1 = *(const bf16x8*)(qrow + 32);

  float mrow[4], lrow[4];
  f32x4 oacc[4];
  const f32x4 zero = {0.f, 0.f, 0.f, 0.f};
#pragma unroll
  for (int r = 0; r < 4; ++r) { mrow[r] = -1e30f; lrow[r] = 0.f; }
#pragma unroll
  for (int t = 0; t < 4; ++t) oacc[t] = zero;

  const int i0 = q0 + wave * 16 + quad * 4;
  bf16* Psw = Ps[wave];
  bf16x8 vpA[4], vpB[4];

  if (qt >= 4) {
    loadv<8>(Vb, q0 - 256, vpA);
    attn_phase<8, 1, 8>(q0 - 256, q0 - 128, Kb, Vb, Vt[0], Psw, vpA, vpB, qa0, qa1, i0, mrow, lrow, oacc);
    attn_phase<8, 0, 4>(q0 - 128, q0, Kb, Vb, Vt[1], Psw, vpB, vpA, qa0, qa1, i0, mrow, lrow, oacc);
    attn_phase<4, 2, 0>(q0, 0, Kb, Vb, Vt[0], Psw, vpA, vpB, qa0, qa1, i0, mrow, lrow, oacc);
  } else if (qt == 3) {
    loadv<4>(Vb, 0, vpA);
    attn_phase<4, 0, 8>(0, 64, Kb, Vb, Vt[0], Psw, vpA, vpB, qa0, qa1, i0, mrow, lrow, oacc);
    attn_phase<8, 0, 4>(64, 192, Kb, Vb, Vt[1], Psw, vpB, vpA, qa0, qa1, i0, mrow, lrow, oacc);
    attn_phase<4, 2, 0>(192, 0, Kb, Vb, Vt[0], Psw, vpA, vpB, qa0, qa1, i0, mrow, lrow, oacc);
  } else if (qt == 2) {
    loadv<8>(Vb, 0, vpA);
    attn_phase<8, 0, 4>(0, 128, Kb, Vb, Vt[0], Psw, vpA, vpB, qa0, qa1, i0, mrow, lrow, oacc);
    attn_phase<4, 2, 0>(128, 0, Kb, Vb, Vt[1], Psw, vpB, vpA, qa0, qa1, i0, mrow, lrow, oacc);
  } else if (qt == 1) {
    loadv<4>(Vb, 0, vpA);
    attn_phase<4, 0, 4>(0, 64, Kb, Vb, Vt[0], Psw, vpA, vpB, qa0, qa1, i0, mrow, lrow, oacc);
    attn_phase<4, 2, 0>(64, 0, Kb, Vb, Vt[1], Psw, vpB, vpA, qa0, qa1, i0, mrow, lrow, oacc);
  } else {
    loadv<4>(Vb, 0, vpA);
    attn_phase<4, 2, 0>(0, 0, Kb, Vb, Vt[0], Psw, vpA, vpB, qa0, qa1, i0, mrow, lrow, oacc);
  }

  // epilogue: normalize, write [B,S,H*HD] bf16
#pragma unroll
  for (int r = 0; r < 4; ++r) {
    const float inv = 1.f / lrow[r];
    const int row = q0 + wave * 16 + quad * 4 + r;
    const size_t outb = ((size_t)(b * 2048 + row)) * 1024 + h * 64;
#pragma unroll
    for (int ht = 0; ht < 4; ++ht)
      Ao[outb + ht * 16 + l16] = (bf16)(oacc[ht][r] * inv);
  }
}

// ---------------------------------------------------------------------------
// Output GEMM: Ao[4096,1024] @ Wo + bo -> fp32 out. 128x64 tile, BK=64,
// ring-2 double-buffered with counted vmcnt(6) gates (raw barriers: loads
// stay in flight across phases). 512 blocks = 2/CU, 48 KiB LDS.
// ---------------------------------------------------------------------------
__global__ __launch_bounds__(256) void out_gemm(const bf16* __restrict__ Ain,
                                                const bf16* __restrict__ WoT,
                                                const float* __restrict__ bo,
                                                float* __restrict__ out) {
  __shared__ bf16 As[2][128 * 64] __attribute__((aligned(16)));
  __shared__ bf16 Bs[2][64 * 64] __attribute__((aligned(16)));
  const int tid = threadIdx.x, lane = tid & 63, wave = tid >> 6;
  const int wm = wave >> 1, wn = wave & 1;
  const int quad = lane >> 4, l16 = lane & 15;
  const int m0 = blockIdx.y * 128, n0 = blockIdx.x * 64;

  f32x4 acc[4][2];
  const f32x4 zero = {0.f, 0.f, 0.f, 0.f};
#pragma unroll
  for (int i = 0; i < 4; ++i)
#pragma unroll
    for (int j = 0; j < 2; ++j) acc[i][j] = zero;

  // stage tile t into buf t&1: A 4 chunks/thread, B 2 chunks/thread (6 total)
#define OUT_STAGE(t)                                                                \
  {                                                                                 \
    const int _buf = (t) & 1;                                                       \
    const int _k0 = (t) * 64;                                                       \
    _Pragma("unroll")                                                               \
    for (int _i = 0; _i < 4; ++_i) {                                                \
      const int chunk = _i * 256 + tid;                                             \
      const int row = chunk >> 3, cg = (chunk & 7) ^ (row & 7);                     \
      ldsdma16(Ain + (size_t)(m0 + row) * 1024 + _k0 + cg * 8,                      \
               (char*)As[_buf] + (size_t)(_i * 256 + wave * 64) * 16);              \
    }                                                                               \
    _Pragma("unroll")                                                               \
    for (int _i = 0; _i < 2; ++_i) {                                                \
      const int chunk = _i * 256 + tid;                                             \
      const int row = chunk >> 3, cg = (chunk & 7) ^ (row & 7);                     \
      ldsdma16(WoT + (size_t)(n0 + row) * 1024 + _k0 + cg * 8,                      \
               (char*)Bs[_buf] + (size_t)(_i * 256 + wave * 64) * 16);              \
    }                                                                               \
  }

  OUT_STAGE(0);
  for (int t = 0; t < 16; ++t) {
    if (t < 15) {
      OUT_STAGE(t + 1);
      asm volatile("s_waitcnt vmcnt(6)" ::: "memory");  // tile t's 6 loads landed
    } else {
      asm volatile("s_waitcnt vmcnt(0)" ::: "memory");
    }
    __builtin_amdgcn_s_barrier();  // all waves' tile-t data in LDS
    bf16x8 aF[4][2], bF[2][2];
    const bf16x8* ha = (const bf16x8*)As[t & 1];
#pragma unroll
    for (int mf = 0; mf < 4; ++mf) {
      const int row = wm * 64 + mf * 16 + l16;
      aF[mf][0] = ha[row * 8 + (quad ^ (row & 7))];
      aF[mf][1] = ha[row * 8 + ((4 + quad) ^ (row & 7))];
    }
    const bf16x8* hb = (const bf16x8*)Bs[t & 1];
#pragma unroll
    for (int nf = 0; nf < 2; ++nf) {
      const int row = wn * 32 + nf * 16 + l16;
      bF[nf][0] = hb[row * 8 + (quad ^ (row & 7))];
      bF[nf][1] = hb[row * 8 + ((4 + quad) ^ (row & 7))];
    }
    __builtin_amdgcn_s_setprio(1);
#pragma unroll
    for (int mf = 0; mf < 4; ++mf)
#pragma unroll
      for (int nf = 0; nf < 2; ++nf)
#pragma unroll
        for (int kk = 0; kk < 2; ++kk)
          acc[mf][nf] = MFMA16(aF[mf][kk], bF[nf][kk], acc[mf][nf]);
    __builtin_amdgcn_s_setprio(0);
    __builtin_amdgcn_s_barrier();  // frag reads done before buf reuse
  }
#undef OUT_STAGE

#pragma unroll
  for (int j = 0; j < 2; ++j) {
    const int n = n0 + wn * 32 + j * 16 + l16;
    const float bias = bo[n];
#pragma unroll
    for (int i = 0; i < 4; ++i) {
#pragma unroll
      for (int r = 0; r < 4; ++r) {
        const int token = m0 + wm * 64 + i * 16 + quad * 4 + r;
        out[(size_t)token * 1024 + n] = acc[i][j][r] + bias;
      }
    }
  }
}

// ---------------------------------------------------------------------------
extern "C" void kernel_launch(void* const* d_in, const int* in_sizes, int n_in,
                              void* d_out, int out_size, void* d_ws, size_t ws_size,
                              hipStream_t stream) {
  const float* x  = (const float*)d_in[0];
  const float* Wq = (const float*)d_in[1];
  const float* bq = (const float*)d_in[2];
  const float* Wk = (const float*)d_in[3];
  const float* bk = (const float*)d_in[4];
  const float* Wv = (const float*)d_in[5];
  const float* bv = (const float*)d_in[6];
  const float* Wo = (const float*)d_in[7];
  const float* bo = (const float*)d_in[8];
  float* out = (float*)d_out;

  char* ws = (char*)d_ws;
  bf16* xb = (bf16*)(ws);                      //  8 MB  x bf16
  bf16* WT = (bf16*)(ws + ((size_t)8 << 20));  //  8 MB  WqT|WkT|WvT|WoT bf16 [n][k]
  bf16* Qd = (bf16*)(ws + ((size_t)16 << 20)); //  8 MB  [B,H,S,HD]
  bf16* Kd = (bf16*)(ws + ((size_t)24 << 20)); //  8 MB
  bf16* Vd = (bf16*)(ws + ((size_t)32 << 20)); //  8 MB
  bf16* Ao = (bf16*)(ws + ((size_t)40 << 20)); //  8 MB  [B,S,DIM]

  prep_kernel<<<dim3(16, 16, 5), 256, 0, stream>>>(x, Wq, Wk, Wv, Wo, xb, WT);
  qkv_gemm<<<dim3(24, 32), 256, 0, stream>>>(xb, WT, bq, bk, bv, Qd, Kd, Vd);
  attn_kernel<<<dim3(32, 16, 2), 256, 0, stream>>>(Qd, Kd, Vd, Ao);
  out_gemm<<<dim3(16, 32), 256, 0, stream>>>(Ao, WT + (size_t)3 * 1024 * 1024, bo, out);
}